// Round 4
// baseline (506.406 us; speedup 1.0000x reference)
//
#include <hip/hip_runtime.h>
#include <cstdint>
#include <cstddef>

// Problem constants: B=128, L=64, F=3072, D=1024, CV=512, CN=1024, MAX_K=8
typedef unsigned short u16;
typedef __attribute__((ext_vector_type(8))) short short8;   // 8 x bf16 (4 VGPRs)
typedef __attribute__((ext_vector_type(4))) float f32x4;    // MFMA accumulator

static __device__ __forceinline__ float bf2f(u16 h) {
  union { unsigned u; float f; } a; a.u = ((unsigned)h) << 16; return a.f;
}
static __device__ __forceinline__ u16 f2bf(float x) {
  union { float f; unsigned u; } a; a.f = x;
  return (u16)((a.u + 0x7fffu + ((a.u >> 16) & 1u)) >> 16);  // RNE
}

// async global->LDS, 16B per lane. LDS dest is wave-uniform base + lane*16.
#define GLDS16(gp, lp)                                                          \
  __builtin_amdgcn_global_load_lds(                                             \
      (const __attribute__((address_space(1))) void*)(gp),                      \
      (__attribute__((address_space(3))) void*)(lp), 16, 0, 0)

template<int N> static __device__ __forceinline__ void vmwait() {
  if constexpr (N == 0)      asm volatile("s_waitcnt vmcnt(0)" ::: "memory");
  else if constexpr (N == 6) asm volatile("s_waitcnt vmcnt(6)" ::: "memory");
}

// ------------------------------------------------------------- merged prep
// Grid-strided: [0,2048) cast ×12/thread; [2048,2816) transpose ×12 tiles;
// [2816,3328) verb-weight prep; [3328,4352) noun-weight prep; [4352,5376) e1pad pad.
__global__ void prep_all(const float* __restrict__ inputs, u16* __restrict__ Xbf,
                         const float* __restrict__ W0, const float* __restrict__ W1,
                         const float* __restrict__ W2, u16* __restrict__ Wt,
                         const float* __restrict__ Kv, const float* __restrict__ bv,
                         const float* __restrict__ g_v, const float* __restrict__ beta_v,
                         const float* __restrict__ mean_v, const float* __restrict__ var_v,
                         u16* __restrict__ KVt, float* __restrict__ biasv,
                         const float* __restrict__ Kn, const float* __restrict__ bnb,
                         const float* __restrict__ g_n, const float* __restrict__ beta_n,
                         const float* __restrict__ mean_n, const float* __restrict__ var_n,
                         u16* __restrict__ KNt, float* __restrict__ biasn,
                         u16* __restrict__ e1pad) {
  __shared__ float tile[32][33];
  const int id = blockIdx.x;
  const int tid = threadIdx.x;
  if (id < 2048) {                        // cast: 12 float4 per thread, grid-stride
    int i = id * 256 + tid;               // total 2048*256*12 = 6291456 exactly
#pragma unroll
    for (int it = 0; it < 12; it++) {
      float4 v = ((const float4*)inputs)[i];
      ushort4 o;
      o.x = f2bf(v.x); o.y = f2bf(v.y); o.z = f2bf(v.z); o.w = f2bf(v.w);
      ((ushort4*)Xbf)[i] = o;
      i += 2048 * 256;
    }
  } else if (id < 2816) {                 // transpose W: 768 blocks x 12 tiles = 9216
    const int tx = tid & 31, ty = tid >> 5;
    for (int it = 0; it < 12; it++) {
      const int tl = (id - 2048) + 768 * it;
      const int kb = (tl % 96) * 32;
      const int jb = (tl / 96) * 32;
      const int w = jb >> 10;
      const float* W = (w == 0) ? W0 : ((w == 1) ? W1 : W2);
      const int nb = jb & 1023;
#pragma unroll
      for (int i = 0; i < 4; i++)
        tile[ty + 8 * i][tx] = W[(size_t)(kb + ty + 8 * i) * 1024 + nb + tx];
      __syncthreads();
#pragma unroll
      for (int i = 0; i < 4; i++)
        Wt[(size_t)(jb + ty + 8 * i) * 3072 + kb + tx] = f2bf(tile[tx][ty + 8 * i]);
      __syncthreads();
    }
  } else if (id < 3328) {                 // prep_kv
    const int c = id - 2816;
    const float scale = g_v[c] * rsqrtf(var_v[c] + 1e-5f);
    for (int t = 0; t < 3; t++)
      for (int d = tid; d < 1024; d += 256)
        KVt[(size_t)c * 3072 + t * 1024 + d] = f2bf(Kv[(size_t)c * 3072 + d * 3 + t] * scale);
    if (tid == 0) biasv[c] = (bv[c] - mean_v[c]) * scale + beta_v[c];
  } else if (id < 4352) {                 // prep_kn
    const int c = id - 3328;
    const float scale = g_n[c] * rsqrtf(var_n[c] + 1e-5f);
    for (int d = tid; d < 1024; d += 256)
      KNt[(size_t)c * 1024 + d] = f2bf(Kn[(size_t)c * 1024 + d] * scale);
    if (tid == 0) biasn[c] = (bnb[c] - mean_n[c]) * scale + beta_n[c];
  } else {                                // zero pad rows 0,65 of e1pad (B,66,D)
    const int i = (id - 4352) * 256 + tid;    // 0..262143
    const int b = i >> 11;
    const int j = i & 2047;
    const int r = (j < 1024) ? 0 : 65;
    const int d = j & 1023;
    e1pad[(size_t)(b * 66 + r) * 1024 + d] = 0;
  }
}

// =====================================================================
// GEMM core: tile 128x256, BK=32, 256 threads = 4 waves, per-wave 128x64
// (acc[8][4]) -> reads/MFMA matches m201 (6 b128 per 16 MFMA avg).
// LDS ring-3: slot = A[128][32] (8KB) + B[256][32] (16KB) = 24KB; 72KB/block
// -> 2 blocks/CU (independent barriers decouple the phase locksteps).
//
// Per tile, two phases (m201 shape):
//  ph1: 8 ds_read_b128 (fa0-3, fb0-3) | 3 GLDS (A0,A1,B0 of t+2) | barrier
//       | setprio1 | 16 MFMA (rows 0-63) | setprio0 | barrier
//  ph2: 4 ds_read_b128 (fa4-7; fb reused in regs) | 3 GLDS (B1-B3) | barrier
//       | setprio1 | 16 MFMA (rows 64-127) | setprio0 | vmcnt(6) | barrier
// vmcnt(6) retires stage(t+1) (oldest 6), leaves stage(t+2) in flight.
//
// Swizzle (verified 0-conflict in r3): row 64B = 4 chunks; chunk c of row r
// at position (c+(r>>1))&3. LDS dest linear; GLOBAL source pre-swizzled
// (rule #21): lane covering (row r, pos p) reads chunk (p-(r>>1))&3.
// Read side: pos = ((quad + (l15>>1))&3), yielding logical chunk = quad.
// =====================================================================
#define SLOTU 12288   // u16 per ring slot (24 KB)

#define STG_H0(SL, K)                                                           \
  { GLDS16(srcA0 + (K), dA0 + (SL) * SLOTU);                                    \
    GLDS16(srcA1 + (K), dA1 + (SL) * SLOTU);                                    \
    GLDS16(srcB0 + (K), dB0 + (SL) * SLOTU); }
#define STG_H1(SL, K)                                                           \
  { GLDS16(srcB1 + (K), dB1 + (SL) * SLOTU);                                    \
    GLDS16(srcB2 + (K), dB2 + (SL) * SLOTU);                                    \
    GLDS16(srcB3 + (K), dB3 + (SL) * SLOTU); }

#define BODY_(SL, NSL, T)                                                       \
  {                                                                             \
    const int t_ = (T);                                                         \
    const bool st_ = (t_ + 2 < NT);                                             \
    const size_t k2_ = (size_t)(t_ + 2) * 32;                                   \
    const u16* ra = rdA + (SL) * SLOTU;                                         \
    const u16* rb = rdB + (SL) * SLOTU;                                         \
    short8 fa[4], fb[4];                                                        \
    _Pragma("unroll")                                                           \
    for (int j = 0; j < 4; j++) fb[j] = *(const short8*)(rb + j * 512);         \
    _Pragma("unroll")                                                           \
    for (int i = 0; i < 4; i++) fa[i] = *(const short8*)(ra + i * 512);         \
    if (st_) STG_H0(NSL, k2_);                                                  \
    __builtin_amdgcn_s_barrier();                                               \
    __builtin_amdgcn_s_setprio(1);                                              \
    _Pragma("unroll")                                                           \
    for (int i = 0; i < 4; i++)                                                 \
      _Pragma("unroll")                                                         \
      for (int j = 0; j < 4; j++)                                               \
        acc[i][j] = __builtin_amdgcn_mfma_f32_16x16x32_bf16(fa[i], fb[j],       \
                                                            acc[i][j], 0, 0, 0);\
    __builtin_amdgcn_s_setprio(0);                                              \
    __builtin_amdgcn_s_barrier();                                               \
    _Pragma("unroll")                                                           \
    for (int i = 0; i < 4; i++) fa[i] = *(const short8*)(ra + 2048 + i * 512);  \
    if (st_) STG_H1(NSL, k2_);                                                  \
    __builtin_amdgcn_s_barrier();                                               \
    __builtin_amdgcn_s_setprio(1);                                              \
    _Pragma("unroll")                                                           \
    for (int i = 0; i < 4; i++)                                                 \
      _Pragma("unroll")                                                         \
      for (int j = 0; j < 4; j++)                                               \
        acc[4 + i][j] = __builtin_amdgcn_mfma_f32_16x16x32_bf16(fa[i], fb[j],   \
                                                      acc[4 + i][j], 0, 0, 0);  \
    __builtin_amdgcn_s_setprio(0);                                              \
    if (t_ < NT - 2) vmwait<6>();                                               \
    else if (t_ == NT - 2) vmwait<0>();                                         \
    __builtin_amdgcn_s_barrier();                                               \
  }

// Abase points at element (m0, 0) (row-major, ldA); Bbase at (n0, 0) (ldB).
// IM2COL: A row r remapped r -> r + 2*(r>>6) (e1pad padded layout, ldA=1024).
template<int NT, bool IM2COL>
static __device__ __forceinline__ void gemm_core(
    const u16* __restrict__ Abase, const int ldA,
    const u16* __restrict__ Bbase, const int ldB,
    u16* lds, f32x4 (*acc)[4]) {
  const int tid = threadIdx.x;
  const int l = tid & 63;
  const int w = tid >> 6;                  // wave 0..3 (= wn, col group)
  const int l15 = l & 15, quad = l >> 4;
  const int lr = l >> 2;                   // row within 16-row region
  const int lpos = l & 3;                  // chunk position 0..3

  // staging sources (pre-swizzled) + linear LDS dests
  const u16 *srcA0, *srcA1, *srcB0, *srcB1, *srcB2, *srcB3;
  u16 *dA0, *dA1, *dB0, *dB1, *dB2, *dB3;
  {
    const int r0 = (0 * 4 + w) * 16 + lr;
    const int r1 = (1 * 4 + w) * 16 + lr;
    const int c0 = (lpos - (r0 >> 1)) & 3;
    const int c1 = (lpos - (r1 >> 1)) & 3;
    const int rr0 = IM2COL ? (r0 + 2 * (r0 >> 6)) : r0;
    const int rr1 = IM2COL ? (r1 + 2 * (r1 >> 6)) : r1;
    srcA0 = Abase + (size_t)rr0 * ldA + c0 * 8;
    srcA1 = Abase + (size_t)rr1 * ldA + c1 * 8;
    dA0 = lds + (0 * 4 + w) * 512;
    dA1 = lds + (1 * 4 + w) * 512;
  }
#pragma unroll
  for (int g = 0; g < 4; g++) {
    const int r = (g * 4 + w) * 16 + lr;
    const int c = (lpos - (r >> 1)) & 3;
    const u16* s = Bbase + (size_t)r * ldB + c * 8;
    u16* d = lds + 4096 + (g * 4 + w) * 512;
    if (g == 0) { srcB0 = s; dB0 = d; }
    else if (g == 1) { srcB1 = s; dB1 = d; }
    else if (g == 2) { srcB2 = s; dB2 = d; }
    else { srcB3 = s; dB3 = d; }
  }
  const int psw = ((quad + (l15 >> 1)) & 3) * 8;
  const u16* rdA = lds + l15 * 32 + psw;                  // + i*512
  const u16* rdB = lds + 4096 + (w * 64 + l15) * 32 + psw; // + j*512

  // prologue: stage tiles 0,1 into slots 0,1 (6 loads each)
  STG_H0(0, 0); STG_H1(0, 0);
  STG_H0(1, 32); STG_H1(1, 32);
  vmwait<6>();                             // tile 0 landed; tile 1 in flight
  __builtin_amdgcn_s_barrier();

  int t = 0;
#pragma unroll 1
  for (; t + 3 <= NT; t += 3) {
    BODY_(0, 2, t);
    BODY_(1, 0, t + 1);
    BODY_(2, 1, t + 2);
  }
  if constexpr (NT % 3 == 2) { BODY_(0, 2, NT - 2); BODY_(1, 0, NT - 1); }
  else if constexpr (NT % 3 == 1) { BODY_(0, 2, NT - 1); }
}

// epilogue: sigmoid + per-column top-8 + mean of top-k; per-wave 128 rows
// = 2 batches (rows 0-63 -> batch m0/64, rows 64-127 -> +1).
static __device__ __forceinline__ void topk_epilogue(
    f32x4 (*acc)[4], const float* __restrict__ bias,
    const int* __restrict__ lens, float* __restrict__ out,
    const int NC, const int m0, const int n0) {
  const int tid = threadIdx.x;
  const int l = tid & 63;
  const int wn = tid >> 6;
  const int l15 = l & 15, quad = l >> 4;
#pragma unroll
  for (int bs = 0; bs < 2; bs++) {
    const int b = (m0 >> 6) + bs;
    const int len = lens[b];
    const int kk8 = (len + 7) >> 3;        // ceil(len/8), 1..8
#pragma unroll
    for (int j = 0; j < 4; j++) {
      const int c = n0 + wn * 64 + j * 16 + l15;
      const float bias_c = bias[c];
      float t[8];
#pragma unroll
      for (int q8 = 0; q8 < 8; q8++) t[q8] = -1e30f;
#pragma unroll
      for (int i2 = 0; i2 < 4; i2++) {
#pragma unroll
        for (int r = 0; r < 4; r++) {
          const int lrow = i2 * 16 + quad * 4 + r;
          const float v = acc[bs * 4 + i2][j][r] + bias_c;
          const float sg = 1.0f / (1.0f + __expf(-v));
          float x = (lrow < len) ? sg : -1e30f;
#pragma unroll
          for (int q8 = 0; q8 < 8; q8++) {  // branchless sorted insert (desc)
            const float hi = fmaxf(t[q8], x);
            x = fminf(t[q8], x);
            t[q8] = hi;
          }
        }
      }
      // merge top-8 lists across the 4 quads (lanes ^16, ^32); snapshot first.
#pragma unroll
      for (int mask = 16; mask <= 32; mask <<= 1) {
        float xs[8];
#pragma unroll
        for (int q8 = 0; q8 < 8; q8++) xs[q8] = __shfl_xor(t[q8], mask);
#pragma unroll
        for (int q8 = 0; q8 < 8; q8++) {
          float x = xs[q8];
#pragma unroll
          for (int p8 = 0; p8 < 8; p8++) {
            const float hi = fmaxf(t[p8], x);
            x = fminf(t[p8], x);
            t[p8] = hi;
          }
        }
      }
      if (quad == 0) {
        float s = 0.f;
#pragma unroll
        for (int q8 = 0; q8 < 8; q8++) s += (q8 < kk8) ? t[q8] : 0.f;
        out[(size_t)b * NC + c] = s / (float)kk8;
      }
    }
  }
}

// ------------------------------------------------------------------ embed GEMM
// grid (12, 64): tile 128x256. 768 blocks at 2 blocks/CU.
__global__ __launch_bounds__(256, 2) void gemm_embed(
    const u16* __restrict__ A, const u16* __restrict__ Bmat,
    const float* __restrict__ bias0, const float* __restrict__ bias1,
    const float* __restrict__ bias2,
    float* __restrict__ oute1, float* __restrict__ oute2,
    u16* __restrict__ e0bf, u16* __restrict__ e1pad, u16* __restrict__ e2bf) {
  __shared__ __align__(16) u16 lds[3 * SLOTU];   // 72 KiB
  const int m0 = blockIdx.y * 128;
  const int n0 = blockIdx.x * 256;

  f32x4 acc[8][4];
#pragma unroll
  for (int i = 0; i < 8; i++)
#pragma unroll
    for (int j = 0; j < 4; j++) acc[i][j] = (f32x4){0.f, 0.f, 0.f, 0.f};

  gemm_core<96, false>(A + (size_t)m0 * 3072, 3072,
                       Bmat + (size_t)n0 * 3072, 3072, lds, acc);

  const int tid = threadIdx.x;
  const int l = tid & 63;
  const int wn = tid >> 6;
  const int l15 = l & 15, quad = l >> 4;
#pragma unroll
  for (int j = 0; j < 4; j++) {
    const int cb = n0 + wn * 64 + j * 16;           // 256-tile never straddles 1024
    const int w = cb >> 10;
    const int n = (cb & 1023) + l15;
    const float bias = ((w == 0) ? bias0 : (w == 1) ? bias1 : bias2)[n];
#pragma unroll
    for (int i = 0; i < 8; i++) {
      const int mr = m0 + i * 16 + quad * 4;
#pragma unroll
      for (int r = 0; r < 4; r++) {
        const int m = mr + r;
        const float v = acc[i][j][r] + bias;
        if (w == 0) {
          e0bf[(size_t)m * 1024 + n] = f2bf(v);
        } else if (w == 1) {
          oute1[(size_t)m * 1024 + n] = v;
          e1pad[(size_t)((m >> 6) * 66 + (m & 63) + 1) * 1024 + n] = f2bf(v);
        } else {
          oute2[(size_t)m * 1024 + n] = v;
          e2bf[(size_t)m * 1024 + n] = f2bf(v);
        }
      }
    }
  }
}

// fused tail: [0,128) verb (K=3072 im2col, NC=512, tiles 128x256);
// [128,384) noun (K=1024, NC=1024); [384,512) attention. 512 blocks @ 2/CU.
__global__ __launch_bounds__(256, 2) void fused_tail(
    const u16* __restrict__ e1pad, const u16* __restrict__ KVt,
    const float* __restrict__ biasv,
    const u16* __restrict__ e2bf, const u16* __restrict__ KNt,
    const float* __restrict__ biasn,
    const u16* __restrict__ e0bf, const float* __restrict__ w_attn,
    const float* __restrict__ b_attn, const int* __restrict__ lens,
    float* __restrict__ out_sent, float* __restrict__ out_ilv,
    float* __restrict__ out_iln) {
  __shared__ __align__(16) u16 smem[3 * SLOTU];   // 72 KiB
  const int id = blockIdx.x;
  const int tid = threadIdx.x;
  if (id < 384) {
    f32x4 acc[8][4];
#pragma unroll
    for (int i = 0; i < 8; i++)
#pragma unroll
      for (int j = 0; j < 4; j++) acc[i][j] = (f32x4){0.f, 0.f, 0.f, 0.f};
    if (id < 128) {
      // verb: A row m = m0+r is the contiguous 3072 u16 at
      // e1pad[((m>>6)*66 + (m&63))*1024] (flat 3-tap im2col); row remap
      // r -> r + 2*(r>>6) relative to base (by*2*66)*1024.
      const int by = id >> 1, bx = id & 1;
      const int n0 = bx * 256;
      gemm_core<96, true>(e1pad + (size_t)(by * 2) * 66 * 1024, 1024,
                          KVt + (size_t)n0 * 3072, 3072, smem, acc);
      topk_epilogue(acc, biasv, lens, out_ilv, 512, by * 128, n0);
    } else {
      const int id2 = id - 128;
      const int by = id2 >> 2, bx = id2 & 3;
      const int m0 = by * 128, n0 = bx * 256;
      gemm_core<32, false>(e2bf + (size_t)m0 * 1024, 1024,
                           KNt + (size_t)n0 * 1024, 1024, smem, acc);
      topk_epilogue(acc, biasn, lens, out_iln, 1024, m0, n0);
    }
  } else {
    // ---- attention pooling, one block (256 thr) per batch
    const int b = id - 384;
    const int lane = tid & 63;
    const int warp = tid >> 6;
    float* sc = (float*)smem;        // 64 floats
    float* at = sc + 64;             // 64 floats
    const int len = lens[b];
    for (int t = 0; t < 16; t++) {
      const int lrow = warp * 16 + t;
      const u16* row = e0bf + (size_t)(b * 64 + lrow) * 1024;
      float s = 0.f;
#pragma unroll
      for (int uu = 0; uu < 16; uu++) {
        const int d = lane + uu * 64;
        s += bf2f(row[d]) * w_attn[d];
      }
#pragma unroll
      for (int off = 32; off > 0; off >>= 1) s += __shfl_down(s, off);
      if (lane == 0) sc[lrow] = s + b_attn[0];
    }
    __syncthreads();
    if (warp == 0) {
      float v = (lane < len) ? sc[lane] : -1e30f;
      float m = v;
#pragma unroll
      for (int off = 32; off > 0; off >>= 1) m = fmaxf(m, __shfl_xor(m, off));
      float p = (lane < len) ? __expf(v - m) : 0.f;
      float ssum = p;
#pragma unroll
      for (int off = 32; off > 0; off >>= 1) ssum += __shfl_xor(ssum, off);
      at[lane] = p / ssum;
    }
    __syncthreads();
    const int d0 = tid * 4;
    float a0 = 0.f, a1 = 0.f, a2 = 0.f, a3 = 0.f;
    for (int lrow = 0; lrow < 64; lrow++) {
      const float wgt = at[lrow];
      const ushort4 u4 = *(const ushort4*)(e0bf + (size_t)(b * 64 + lrow) * 1024 + d0);
      a0 += wgt * bf2f(u4.x);
      a1 += wgt * bf2f(u4.y);
      a2 += wgt * bf2f(u4.z);
      a3 += wgt * bf2f(u4.w);
    }
    float4 o; o.x = a0; o.y = a1; o.z = a2; o.w = a3;
    *(float4*)(out_sent + (size_t)b * 1024 + d0) = o;
  }
}

// --------------------------------------------------------------------- launch
extern "C" void kernel_launch(void* const* d_in, const int* in_sizes, int n_in,
                              void* d_out, int out_size, void* d_ws, size_t ws_size,
                              hipStream_t stream) {
  const float* inputs = (const float*)d_in[0];
  const int*   lens   = (const int*)d_in[1];
  const float* W0 = (const float*)d_in[2];
  const float* b0 = (const float*)d_in[3];
  const float* W1 = (const float*)d_in[4];
  const float* b1 = (const float*)d_in[5];
  const float* W2 = (const float*)d_in[6];
  const float* b2 = (const float*)d_in[7];
  const float* w_attn = (const float*)d_in[8];
  const float* b_attn = (const float*)d_in[9];
  const float* Kv   = (const float*)d_in[10];
  const float* bv   = (const float*)d_in[11];
  const float* g_v  = (const float*)d_in[12];
  const float* beta_v = (const float*)d_in[13];
  const float* mean_v = (const float*)d_in[14];
  const float* var_v  = (const float*)d_in[15];
  const float* Kn   = (const float*)d_in[16];
  const float* bn_b = (const float*)d_in[17];
  const float* g_n  = (const float*)d_in[18];
  const float* beta_n = (const float*)d_in[19];
  const float* mean_n = (const float*)d_in[20];
  const float* var_n  = (const float*)d_in[21];

  float* out = (float*)d_out;
  float* out_sent = out;                               // (128,1024)
  float* out_e1   = out + 131072;                      // (128,64,1024)
  float* out_e2   = out + 131072 + 8388608;            // (128,64,1024)
  float* out_ilv  = out + 131072 + 2 * 8388608;        // (128,512)
  float* out_iln  = out_ilv + 65536;                   // (128,1024)

  // workspace carve
  char* p = (char*)d_ws;
  u16* Xbf  = (u16*)p; p += (size_t)8192 * 3072 * 2;   // inputs bf16
  u16* Wt   = (u16*)p; p += (size_t)3072 * 3072 * 2;   // [W0|W1|W2]^T, N-major
  u16* KVt  = (u16*)p; p += (size_t)512 * 3072 * 2;    // verb weights, BN-folded
  u16* KNt  = (u16*)p; p += (size_t)1024 * 1024 * 2;   // noun weights, BN-folded
  float* biasv = (float*)p; p += 512 * 4;
  float* biasn = (float*)p; p += 1024 * 4;
  u16* e0bf  = (u16*)p; p += (size_t)8192 * 1024 * 2;
  u16* e1pad = (u16*)p; p += (size_t)128 * 66 * 1024 * 2;  // (B,66,D) zero-padded
  u16* e2bf  = (u16*)p; p += (size_t)8192 * 1024 * 2;

  prep_all<<<5376, 256, 0, stream>>>(inputs, Xbf, W0, W1, W2, Wt,
                                     Kv, bv, g_v, beta_v, mean_v, var_v, KVt, biasv,
                                     Kn, bn_b, g_n, beta_n, mean_n, var_n, KNt, biasn,
                                     e1pad);
  gemm_embed<<<dim3(12, 64), 256, 0, stream>>>(Xbf, Wt, b0, b1, b2, out_e1, out_e2,
                                               e0bf, e1pad, e2bf);
  fused_tail<<<512, 256, 0, stream>>>(e1pad, KVt, biasv, e2bf, KNt, biasn,
                                      e0bf, w_attn, b_attn, lens,
                                      out_sent, out_ilv, out_iln);
}